// Round 8
// baseline (443.809 us; speedup 1.0000x reference)
//
#include <hip/hip_runtime.h>

typedef __bf16 bf16x8 __attribute__((ext_vector_type(8)));
typedef float f32x4 __attribute__((ext_vector_type(4)));
typedef float f32x16 __attribute__((ext_vector_type(16)));

#define CC 256
#define HH 48
#define WW 64
#define HW (HH * WW)
#define NB 8
#define GW 21

// =========================== DIAGNOSTIC ROUND ==============================
// R15 is a SACRIFICIAL measurement round (pre-committed after 6 structural
// nulls): repeat prep x7 and corr x3 (idempotent re-execution, memory
// clobber between reps) so BOTH kernels exceed the ~42.5us fill threshold
// and surface in the top-5 counter table. Interpretation: true dur = dur/REPS
// (reps 2+ run L2-warm -> mild underestimate). R16 reverts the REPS and
// applies the fix selected by the pre-committed decision tree.
// ===========================================================================
#define PREP_REPS 7
#define CORR_REPS 3

// ---------------------------------------------------------------------------
// Prepass (R14 body, x7): BOTH inputs -> MFMA-fragment PARITY order
//   [b][y][cblk=c>>3][p=x&1][x2=x>>1][c&7] bf16
// in1 scaled by 2^-8 (exact in bf16) to fold the /sumelems.
// ---------------------------------------------------------------------------
__global__ __launch_bounds__(256) void prep_kernel(const float* __restrict__ in1,
                                                   const float* __restrict__ in2,
                                                   unsigned short* __restrict__ o1,
                                                   unsigned short* __restrict__ o2)
{
    __shared__ float lds[CC * 33];
    int blk  = blockIdx.x;
    int sel  = (blk >= 768);
    int blk2 = sel ? blk - 768 : blk;
    int b  = blk2 & 7;
    int st = blk2 >> 3;
    int s0 = st * 32;
    const float* src = sel ? in2 : in1;
    unsigned short* dst = sel ? o2 : o1;
    float scale = sel ? 1.0f : (1.0f / 256.0f);

    int t = threadIdx.x;
    int sidx  = t & 31;
    int cbase = t >> 5;
    const float* sb = src + (size_t)b * CC * HW + s0;

    int y  = s0 >> 6;
    int xb = s0 & 63;
    int s  = t & 31;
    int c8 = t >> 5;
    unsigned short* db = dst + (size_t)(b * HH + y) * 32 * 64 * 8;
    int x = xb + s;
    int xoff = (x & 1) * 32 + (x >> 1);

    for (int rep = 0; rep < PREP_REPS; ++rep) {
        asm volatile("" ::: "memory");           // no CSE across reps
        __syncthreads();                         // WAR: prior rep's lds reads done
        #pragma unroll
        for (int p = 0; p < 32; ++p) {
            int c = cbase + p * 8;
            lds[c * 33 + sidx] = sb[(size_t)c * HW + sidx] * scale;
        }
        __syncthreads();

        #pragma unroll
        for (int it = 0; it < 4; ++it) {
            int cblk = it * 8 + c8;
            unsigned dw[4];
            #pragma unroll
            for (int d = 0; d < 4; ++d) {
                unsigned u0 = __builtin_bit_cast(unsigned, lds[(cblk * 8 + 2 * d) * 33 + s]);
                u0 += 0x7fffu + ((u0 >> 16) & 1u);
                unsigned u1 = __builtin_bit_cast(unsigned, lds[(cblk * 8 + 2 * d + 1) * 33 + s]);
                u1 += 0x7fffu + ((u1 >> 16) & 1u);
                dw[d] = (u0 >> 16) | (u1 & 0xffff0000u);
            }
            *(uint4*)(db + ((size_t)cblk * 64 + xoff) * 8) =
                make_uint4(dw[0], dw[1], dw[2], dw[3]);
        }
    }
}

// ---------------------------------------------------------------------------
// Main (R14 body, x3): zero-barrier independent-wave structure.
// One wave = one (b, ys0, q) computing the j-pair {2q, 2q+1}; A + 2 B rows
// read directly from global (L2) with depth-4/distance-3 register rings;
// wave-private D^T epilogue in LDS; no __syncthreads anywhere.
// ---------------------------------------------------------------------------
__global__ __launch_bounds__(128, 2) void corr_kernel(const unsigned short* __restrict__ in1F,
                                                      const unsigned short* __restrict__ in2F,
                                                      float* __restrict__ out)
{
    __shared__ float dts[2][2304];               // per-wave [pe][32 ce][36 xe]

    int blk = blockIdx.x;
    int b   = blk & 7;                           // batch == XCD affinity
    int r   = blk >> 3;                          // ysrc-major
    int yi  = r / 6;                             // 0..87
    int qh  = r - yi * 6;                        // 0..5
    int ys0 = yi - 20;
    int ys1 = ys0 + 2;

    int tid  = threadIdx.x;
    int w    = tid >> 6;                         // 0..1
    int lane = tid & 63;
    int q    = qh + 6 * w;                       // 0..11
    int yo   = ys0 + 20 - 4 * q;                 // output row (also A row)

    // idle waves exit immediately -- legal: no barriers in this kernel
    if (q > 10 || yo < 0 || yo >= HH) return;

    bool vs_[2];
    vs_[0] = (ys0 >= 0) && (ys0 < HH);
    vs_[1] = (ys1 >= 0) && (ys1 < HH);
    int j0 = 2 * q;

    int l31 = lane & 31;
    int q2  = lane >> 5;
    int lofs = q2 * 512 + l31 * 8;               // fragment base (ushort units)

    // operand bases; frag(kk,p) at + kk*1024 + p*256 (ushorts)
    const unsigned short* ar = in1F + (size_t)(b * HH + yo) * 16384 + lofs;
    const unsigned short* br_[2];
    br_[0] = in2F + (size_t)(b * HH + (vs_[0] ? ys0 : 0)) * 16384 + lofs;
    br_[1] = in2F + (size_t)(b * HH + (vs_[1] ? ys1 : 0)) * 16384 + lofs;

    float* dtw = dts[w];
    int xe = lane >> 1;
    int pe = lane & 1;

    for (int rep = 0; rep < CORR_REPS; ++rep) {
        asm volatile("" ::: "memory");           // no CSE across reps

        // ---- depth-4 / distance-3 rings for BOTH A and B ----
        bf16x8 Ab[4][2], Bb[4][2][2];
        #pragma unroll
        for (int s = 0; s < 3; ++s) {
            #pragma unroll
            for (int p = 0; p < 2; ++p)
                Ab[s][p] = *(const bf16x8*)(ar + s * 1024 + p * 256);
            #pragma unroll
            for (int jj = 0; jj < 2; ++jj)
                if (vs_[jj])
                    #pragma unroll
                    for (int p = 0; p < 2; ++p)
                        Bb[s][jj][p] = *(const bf16x8*)(br_[jj] + s * 1024 + p * 256);
        }

        f32x16 acc[2][2];                        // [jj][parity]
        #pragma unroll
        for (int jj = 0; jj < 2; ++jj)
            #pragma unroll
            for (int p = 0; p < 2; ++p)
                acc[jj][p] = (f32x16)(0.0f);

        #pragma unroll
        for (int kk = 0; kk < 16; ++kk) {
            if (kk < 13) {                       // refill slot kk+3, 3 iters ahead
                #pragma unroll
                for (int p = 0; p < 2; ++p)
                    Ab[(kk + 3) & 3][p] =
                        *(const bf16x8*)(ar + (size_t)(kk + 3) * 1024 + p * 256);
                #pragma unroll
                for (int jj = 0; jj < 2; ++jj)
                    if (vs_[jj])
                        #pragma unroll
                        for (int p = 0; p < 2; ++p)
                            Bb[(kk + 3) & 3][jj][p] =
                                *(const bf16x8*)(br_[jj] + (size_t)(kk + 3) * 1024 + p * 256);
            }
            #pragma unroll
            for (int jj = 0; jj < 2; ++jj)
                if (vs_[jj])
                    #pragma unroll
                    for (int p = 0; p < 2; ++p)
                        acc[jj][p] = __builtin_amdgcn_mfma_f32_32x32x16_bf16(
                            Ab[kk & 3][p], Bb[kk & 3][jj][p], acc[jj][p], 0, 0, 0);
        }

        // Epilogue: wave-private D^T dump + band extract, j0 then j1.
        // 32x32 C layout: col = l31 (n = ce), row = (r&3)+8*(r>>2)+4*q2 (m = xe).
        #pragma unroll
        for (int jj = 0; jj < 2; ++jj) {
            int j = j0 + jj;
            if (j > 20) continue;                // q=10 has no j1
            float* orow = out + (((size_t)(b * 441 + j * GW)) * HH + yo) * WW;
            #pragma unroll
            for (int p = 0; p < 2; ++p)
                #pragma unroll
                for (int rq = 0; rq < 4; ++rq) {
                    f32x4 v = { acc[jj][p][4 * rq], acc[jj][p][4 * rq + 1],
                                acc[jj][p][4 * rq + 2], acc[jj][p][4 * rq + 3] };
                    *(f32x4*)(dtw + (size_t)(p * 32 + l31) * 36 + rq * 8 + q2 * 4) = v;
                }
            #pragma unroll
            for (int jx = 0; jx < GW; ++jx) {
                int ce = xe + jx - 10;           // x = 2*xe+pe, colx = 2*ce+pe
                float val = (ce >= 0 && ce < 32)
                          ? dtw[(size_t)(pe * 32 + ce) * 36 + xe] : 0.0f;
                __builtin_nontemporal_store(val, orow + (size_t)jx * HW + lane);
            }
        }
    }
}

extern "C" void kernel_launch(void* const* d_in, const int* in_sizes, int n_in,
                              void* d_out, int out_size, void* d_ws, size_t ws_size,
                              hipStream_t stream)
{
    (void)in_sizes; (void)n_in; (void)out_size; (void)ws_size;
    const float* in1 = (const float*)d_in[0];
    const float* in2 = (const float*)d_in[1];
    float* out = (float*)d_out;

    unsigned short* in1F = (unsigned short*)d_ws;                 // 12.6 MB
    unsigned short* in2F = in1F + (size_t)NB * HW * CC;           // 12.6 MB

    prep_kernel<<<dim3(1536), dim3(256), 0, stream>>>(in1, in2, in1F, in2F);
    corr_kernel<<<dim3(NB * 88 * 6), dim3(128), 0, stream>>>(in1F, in2F, out);
}

// Round 9
// 113.676 us; speedup vs baseline: 3.9042x; 3.9042x over previous
//
#include <hip/hip_runtime.h>

typedef __bf16 bf16x8 __attribute__((ext_vector_type(8)));
typedef float f32x4 __attribute__((ext_vector_type(4)));
typedef float f32x16 __attribute__((ext_vector_type(16)));

#define CC 256
#define HH 48
#define WW 64
#define HW (HH * WW)
#define NB 8
#define GW 21

// ---------------------------------------------------------------------------
// Prepass (unchanged): BOTH inputs -> MFMA-fragment PARITY order
//   [b][y][cblk=c>>3][p=x&1][x2=x>>1][c&7] bf16
// in1 scaled by 2^-8 (exact in bf16) to fold the /sumelems.
// ---------------------------------------------------------------------------
__global__ __launch_bounds__(256) void prep_kernel(const float* __restrict__ in1,
                                                   const float* __restrict__ in2,
                                                   unsigned short* __restrict__ o1,
                                                   unsigned short* __restrict__ o2)
{
    __shared__ float lds[CC * 33];
    int blk  = blockIdx.x;
    int sel  = (blk >= 768);
    int blk2 = sel ? blk - 768 : blk;
    int b  = blk2 & 7;
    int st = blk2 >> 3;
    int s0 = st * 32;
    const float* src = sel ? in2 : in1;
    unsigned short* dst = sel ? o2 : o1;
    float scale = sel ? 1.0f : (1.0f / 256.0f);

    int t = threadIdx.x;
    int sidx  = t & 31;
    int cbase = t >> 5;
    const float* sb = src + (size_t)b * CC * HW + s0;
    #pragma unroll
    for (int p = 0; p < 32; ++p) {
        int c = cbase + p * 8;
        lds[c * 33 + sidx] = sb[(size_t)c * HW + sidx] * scale;
    }
    __syncthreads();

    int y  = s0 >> 6;
    int xb = s0 & 63;
    int s  = t & 31;
    int c8 = t >> 5;
    unsigned short* db = dst + (size_t)(b * HH + y) * 32 * 64 * 8;
    int x = xb + s;
    int xoff = (x & 1) * 32 + (x >> 1);
    #pragma unroll
    for (int it = 0; it < 4; ++it) {
        int cblk = it * 8 + c8;
        unsigned dw[4];
        #pragma unroll
        for (int d = 0; d < 4; ++d) {
            unsigned u0 = __builtin_bit_cast(unsigned, lds[(cblk * 8 + 2 * d) * 33 + s]);
            u0 += 0x7fffu + ((u0 >> 16) & 1u);
            unsigned u1 = __builtin_bit_cast(unsigned, lds[(cblk * 8 + 2 * d + 1) * 33 + s]);
            u1 += 0x7fffu + ((u1 >> 16) & 1u);
            dw[d] = (u0 >> 16) | (u1 & 0xffff0000u);
        }
        *(uint4*)(db + ((size_t)cblk * 64 + xoff) * 8) =
            make_uint4(dw[0], dw[1], dw[2], dw[3]);
    }
}

// ---------------------------------------------------------------------------
// Main (R16): R14's zero-barrier independent-wave body, regrouped so waves
// SHARING B rows co-reside on one CU (L1 reuse). R14 was L2-request-bound
// (~576MB L2 reads / 22us = 26 TB/s ~ 78% of the 34.5 TB/s L2 ceiling);
// R13's low-volume variant (293MB) was latency-bound at 6 lockstep waves.
// This combines them: block = (b, yi, t), 4 waves, wave w -> q = 4t + w.
// All 4 waves read the SAME two B rows (ys0, ys1 depend only on yi) at
// nearly the same time -> ~3/4 of B reads L1-hit -> L2 volume ~380MB,
// while waves stay fully independent (no barriers; wave-private D^T LDS;
// idle waves exit immediately). LDS 36.9KB/block, launch_bounds(256,2)
// -> 2-3 blocks/CU = 8-12 independent waves/CU.
// Grid 8b x 88 yi x 3 t = 2112 blocks; blocks of one yi are stride-8 apart
// -> same XCD (b = blk&7 affinity preserved).
// ---------------------------------------------------------------------------
__global__ __launch_bounds__(256, 2) void corr_kernel(const unsigned short* __restrict__ in1F,
                                                      const unsigned short* __restrict__ in2F,
                                                      float* __restrict__ out)
{
    __shared__ float dts[4][2304];               // per-wave [pe][32 ce][36 xe]

    int blk = blockIdx.x;
    int b   = blk & 7;                           // batch == XCD affinity
    int r   = blk >> 3;                          // ysrc-major
    int yi  = r / 3;                             // 0..87
    int t   = r - yi * 3;                        // 0..2
    int ys0 = yi - 20;
    int ys1 = ys0 + 2;

    int tid  = threadIdx.x;
    int w    = tid >> 6;                         // 0..3
    int lane = tid & 63;
    int q    = 4 * t + w;                        // 0..11
    int yo   = ys0 + 20 - 4 * q;                 // output row (also A row)

    // idle waves exit immediately -- legal: no barriers in this kernel
    if (q > 10 || yo < 0 || yo >= HH) return;

    bool vs_[2];
    vs_[0] = (ys0 >= 0) && (ys0 < HH);
    vs_[1] = (ys1 >= 0) && (ys1 < HH);
    int j0 = 2 * q;

    int l31 = lane & 31;
    int q2  = lane >> 5;
    int lofs = q2 * 512 + l31 * 8;               // fragment base (ushort units)

    // operand bases; frag(kk,p) at + kk*1024 + p*256 (ushorts)
    const unsigned short* ar = in1F + (size_t)(b * HH + yo) * 16384 + lofs;
    const unsigned short* br_[2];
    br_[0] = in2F + (size_t)(b * HH + (vs_[0] ? ys0 : 0)) * 16384 + lofs;
    br_[1] = in2F + (size_t)(b * HH + (vs_[1] ? ys1 : 0)) * 16384 + lofs;

    // ---- depth-4 / distance-3 rings for BOTH A and B (proven pattern) ----
    bf16x8 Ab[4][2], Bb[4][2][2];
    #pragma unroll
    for (int s = 0; s < 3; ++s) {
        #pragma unroll
        for (int p = 0; p < 2; ++p)
            Ab[s][p] = *(const bf16x8*)(ar + s * 1024 + p * 256);
        #pragma unroll
        for (int jj = 0; jj < 2; ++jj)
            if (vs_[jj])
                #pragma unroll
                for (int p = 0; p < 2; ++p)
                    Bb[s][jj][p] = *(const bf16x8*)(br_[jj] + s * 1024 + p * 256);
    }

    f32x16 acc[2][2];                            // [jj][parity]
    #pragma unroll
    for (int jj = 0; jj < 2; ++jj)
        #pragma unroll
        for (int p = 0; p < 2; ++p)
            acc[jj][p] = (f32x16)(0.0f);

    #pragma unroll
    for (int kk = 0; kk < 16; ++kk) {
        if (kk < 13) {                           // refill slot kk+3, 3 iters ahead
            #pragma unroll
            for (int p = 0; p < 2; ++p)
                Ab[(kk + 3) & 3][p] =
                    *(const bf16x8*)(ar + (size_t)(kk + 3) * 1024 + p * 256);
            #pragma unroll
            for (int jj = 0; jj < 2; ++jj)
                if (vs_[jj])
                    #pragma unroll
                    for (int p = 0; p < 2; ++p)
                        Bb[(kk + 3) & 3][jj][p] =
                            *(const bf16x8*)(br_[jj] + (size_t)(kk + 3) * 1024 + p * 256);
        }
        #pragma unroll
        for (int jj = 0; jj < 2; ++jj)
            if (vs_[jj])
                #pragma unroll
                for (int p = 0; p < 2; ++p)
                    acc[jj][p] = __builtin_amdgcn_mfma_f32_32x32x16_bf16(
                        Ab[kk & 3][p], Bb[kk & 3][jj][p], acc[jj][p], 0, 0, 0);
    }

    // Epilogue: wave-private D^T dump + band extract, j0 then j1.
    // 32x32 C layout: col = l31 (n = ce), row = (r&3) + 8*(r>>2) + 4*q2 (m = xe).
    // Invalid-ysrc jj falls through with acc == 0 -> stores zeros (required).
    float* dtw = dts[w];
    int xe = lane >> 1;
    int pe = lane & 1;
    #pragma unroll
    for (int jj = 0; jj < 2; ++jj) {
        int j = j0 + jj;
        if (j > 20) continue;                    // q=10 has no j1
        float* orow = out + (((size_t)(b * 441 + j * GW)) * HH + yo) * WW;
        #pragma unroll
        for (int p = 0; p < 2; ++p)
            #pragma unroll
            for (int rq = 0; rq < 4; ++rq) {
                f32x4 v = { acc[jj][p][4 * rq], acc[jj][p][4 * rq + 1],
                            acc[jj][p][4 * rq + 2], acc[jj][p][4 * rq + 3] };
                *(f32x4*)(dtw + (size_t)(p * 32 + l31) * 36 + rq * 8 + q2 * 4) = v;
            }
        #pragma unroll
        for (int jx = 0; jx < GW; ++jx) {
            int ce = xe + jx - 10;               // x = 2*xe+pe, colx = 2*ce+pe
            float val = (ce >= 0 && ce < 32)
                      ? dtw[(size_t)(pe * 32 + ce) * 36 + xe] : 0.0f;
            __builtin_nontemporal_store(val, orow + (size_t)jx * HW + lane);
        }
    }
}

extern "C" void kernel_launch(void* const* d_in, const int* in_sizes, int n_in,
                              void* d_out, int out_size, void* d_ws, size_t ws_size,
                              hipStream_t stream)
{
    (void)in_sizes; (void)n_in; (void)out_size; (void)ws_size;
    const float* in1 = (const float*)d_in[0];
    const float* in2 = (const float*)d_in[1];
    float* out = (float*)d_out;

    unsigned short* in1F = (unsigned short*)d_ws;                 // 12.6 MB
    unsigned short* in2F = in1F + (size_t)NB * HW * CC;           // 12.6 MB

    prep_kernel<<<dim3(1536), dim3(256), 0, stream>>>(in1, in2, in1F, in2F);
    corr_kernel<<<dim3(NB * 88 * 3), dim3(256), 0, stream>>>(in1F, in2F, out);
}